// Round 6
// baseline (341.426 us; speedup 1.0000x reference)
//
#include <hip/hip_runtime.h>

// Problem: B=1024, F=64, D_IN=D_OUT=256, H=8, dh=32. f32 in/out, bf16 MFMA compute.
typedef __attribute__((ext_vector_type(8))) short bf16x8;
typedef __attribute__((ext_vector_type(8))) unsigned short u16x8;
typedef __attribute__((ext_vector_type(4))) unsigned short u16x4;
typedef __attribute__((ext_vector_type(4))) float f32x4;
typedef unsigned short u16;

__device__ __forceinline__ float b2f(u16 u) {
    return __builtin_bit_cast(float, (unsigned)u << 16);
}
__device__ __forceinline__ u16 f2b(float f) {  // RNE f32->bf16
    unsigned i = __builtin_bit_cast(unsigned, f);
    return (u16)((i + 0x7FFFu + ((i >> 16) & 1u)) >> 16);
}
__device__ __forceinline__ unsigned pkb(float a, float b) {
    return (unsigned)f2b(a) | ((unsigned)f2b(b) << 16);
}
__device__ __forceinline__ void async_cp16(const u16* g, u16* l) {
    __builtin_amdgcn_global_load_lds((const __attribute__((address_space(1))) void*)g,
                                     (__attribute__((address_space(3))) void*)l, 16, 0, 0);
}

// ---- kernel 0: f32 weights [d][w] -> bf16 WT [w][d]; z==192 converts W_lin (no transpose)
__global__ __launch_bounds__(256) void wtrans_kernel(
    const float* __restrict__ Q, const float* __restrict__ K, const float* __restrict__ V,
    const float* __restrict__ Wl, u16* __restrict__ WT, u16* __restrict__ WlB)
{
    int z = blockIdx.z;
    int tid = threadIdx.x;
    if (z == 192) {  // W_lin [w][d] already B-operand layout; dtype-convert only
        int w0 = blockIdx.x * 64, d0 = blockIdx.y * 64;
#pragma unroll
        for (int i = 0; i < 2; ++i) {
            int idx = tid * 2 + i; int r = idx >> 3; int c8 = (idx & 7) * 8;
            const float* p = Wl + (size_t)(w0 + r) * 256 + d0 + c8;
            f32x4 a = *(const f32x4*)p, b = *(const f32x4*)(p + 4);
            u16x8 v;
            ((unsigned*)&v)[0] = pkb(a[0], a[1]); ((unsigned*)&v)[1] = pkb(a[2], a[3]);
            ((unsigned*)&v)[2] = pkb(b[0], b[1]); ((unsigned*)&v)[3] = pkb(b[2], b[3]);
            *(u16x8*)(WlB + (size_t)(w0 + r) * 256 + d0 + c8) = v;
        }
        return;
    }
    if (z > 192) return;
    int m = z >> 6, f = z & 63;
    const float* src = (m == 0 ? Q : (m == 1 ? K : V)) + (size_t)f * 65536;
    u16* dst = WT + (size_t)z * 65536;
    int w0 = blockIdx.x * 64, d0 = blockIdx.y * 64;
    __shared__ u16 tile[64][68];
#pragma unroll
    for (int i = 0; i < 2; ++i) {
        int idx = tid * 2 + i; int r = idx >> 3; int c8 = (idx & 7) * 8;
        const float* p = src + (size_t)(d0 + r) * 256 + w0 + c8;
        f32x4 a = *(const f32x4*)p, b = *(const f32x4*)(p + 4);
        u16x4 lo, hi;
        ((unsigned*)&lo)[0] = pkb(a[0], a[1]); ((unsigned*)&lo)[1] = pkb(a[2], a[3]);
        ((unsigned*)&hi)[0] = pkb(b[0], b[1]); ((unsigned*)&hi)[1] = pkb(b[2], b[3]);
        *(u16x4*)&tile[r][c8] = lo;
        *(u16x4*)&tile[r][c8 + 4] = hi;
    }
    __syncthreads();
#pragma unroll
    for (int i = 0; i < 2; ++i) {
        int idx = tid * 2 + i; int rw = idx >> 3; int c8 = (idx & 7) * 8;
        u16x8 v;
#pragma unroll
        for (int j = 0; j < 8; ++j) v[j] = tile[c8 + j][rw];
        *(u16x8*)(dst + (size_t)(w0 + rw) * 256 + d0 + c8) = v;
    }
}

// ---- kernel 1: q,k,v per f, m fused. A staged once (swizzled LDS -> regs);
// B via global_load_lds double-buffer, BK=64 (32 MFMA per barrier).
__global__ __launch_bounds__(256, 2) void qkv_gemm_kernel(
    const float* __restrict__ theta, const u16* __restrict__ WT, u16* __restrict__ ws, int B)
{
    int f = blockIdx.z;
    int bm0 = blockIdx.x * 128, bn0 = blockIdx.y * 128;
    __shared__ u16 smem[128 * 256];  // 64KB: phase1 A-tile; phase2 B dbuf 2x16KB
    int tid = threadIdx.x, wave = tid >> 6, lane = tid & 63;
    int l15 = lane & 15, quad = lane >> 4;
    int wm0 = (wave >> 1) * 64, wn0 = (wave & 1) * 64;

    const float* Af = theta + (size_t)f * 256;
#pragma unroll
    for (int p = 0; p < 16; ++p) {
        int id = p * 256 + tid;
        int r = id >> 5, c = id & 31;
        const float* g = Af + (size_t)(bm0 + r) * 16384 + c * 8;
        f32x4 a = *(const f32x4*)g, b = *(const f32x4*)(g + 4);
        u16x8 v;
        ((unsigned*)&v)[0] = pkb(a[0], a[1]); ((unsigned*)&v)[1] = pkb(a[2], a[3]);
        ((unsigned*)&v)[2] = pkb(b[0], b[1]); ((unsigned*)&v)[3] = pkb(b[2], b[3]);
        *(u16x8*)&smem[r * 256 + ((c ^ (r & 7)) * 8)] = v;
    }
    __syncthreads();
    bf16x8 af[4][8];
#pragma unroll
    for (int mi = 0; mi < 4; ++mi)
#pragma unroll
        for (int kk = 0; kk < 8; ++kk) {
            int row = wm0 + mi * 16 + l15;
            int pos = (kk * 4 + quad) ^ (l15 & 7);
            af[mi][kk] = *(const bf16x8*)&smem[row * 256 + pos * 8];
        }
    __syncthreads();  // A reads done before B dbuf overwrites smem

    // 12 iterations: it = m*4 + kp (kp = K-pair index, BK=64)
    auto issueB = [&](int it) {
        int m = it >> 2, kp = it & 3, buf = it & 1;
        const u16* Bt = WT + (size_t)(m * 64 + f) * 65536;
#pragma unroll
        for (int s = 0; s < 2; ++s)
#pragma unroll
            for (int i = 0; i < 2; ++i) {
                int r0 = wave * 32 + i * 16;
                const u16* g = Bt + (size_t)(bn0 + r0 + (lane >> 2)) * 256 + (kp * 2 + s) * 32 + (lane & 3) * 8;
                async_cp16(g, &smem[buf * 8192 + s * 4096 + r0 * 32]);
            }
    };
    issueB(0);
    f32x4 acc[4][4];
#pragma unroll
    for (int it = 0; it < 12; ++it) {
        int kp = it & 3, buf = it & 1;
        if (kp == 0) {
#pragma unroll
            for (int mi = 0; mi < 4; ++mi)
#pragma unroll
                for (int ni = 0; ni < 4; ++ni) acc[mi][ni] = f32x4{0.f, 0.f, 0.f, 0.f};
        }
        __syncthreads();             // current buffer landed
        if (it < 11) issueB(it + 1);
#pragma unroll
        for (int s = 0; s < 2; ++s) {
            bf16x8 bfr[4];
#pragma unroll
            for (int ni = 0; ni < 4; ++ni)
                bfr[ni] = *(const bf16x8*)&smem[buf * 8192 + s * 4096 + (wn0 + ni * 16 + l15) * 32 + quad * 8];
#pragma unroll
            for (int mi = 0; mi < 4; ++mi)
#pragma unroll
                for (int ni = 0; ni < 4; ++ni)
                    acc[mi][ni] = __builtin_amdgcn_mfma_f32_16x16x32_bf16(af[mi][kp * 2 + s], bfr[ni], acc[mi][ni], 0, 0, 0);
        }
        if (kp == 3) {
            int m = it >> 2;
            u16* C = ws + (size_t)m * B * 16384 + (size_t)f * 256;
#pragma unroll
            for (int mi = 0; mi < 4; ++mi)
#pragma unroll
                for (int ni = 0; ni < 4; ++ni)
#pragma unroll
                    for (int r = 0; r < 4; ++r)
                        C[(size_t)(bm0 + wm0 + mi * 16 + quad * 4 + r) * 16384 + bn0 + wn0 + ni * 16 + l15] =
                            f2b(acc[mi][ni][r]);
        }
    }
}

// ---- kernel 2: FUSED attention + linear + LayerNorm. One block per b, 4 waves.
// Wave w handles heads 2w,2w+1 -> attention output lands exactly in the GEMM
// accumulator slice (cols w*64..w*64+63): acc[mi][t*2+n2]. Then res += theta@WlB^T, LN.
__global__ __launch_bounds__(256, 2) void attn_lin_kernel(
    const u16* __restrict__ qws, const u16* __restrict__ kws, const u16* __restrict__ vws,
    const float* __restrict__ theta, const u16* __restrict__ WlB,
    const float* __restrict__ gamma, const float* __restrict__ beta,
    const float* __restrict__ rotw, float* __restrict__ out)
{
    constexpr float INV2PI = 0.15915494309189535f;
    constexpr float LOG2E = 1.4426950408889634f;
    int b = blockIdx.x;
    int tid = threadIdx.x, wave = tid >> 6, lane = tid & 63;
    int l15 = lane & 15, quad = lane >> 4;
    int wn0 = wave * 64;
    // LDS 52KB total -> 3 blocks/CU:
    //   region0 36864B: Sb[4][64][72] (attn)  /  thbf[64][256] swizzled (gemm)
    //   region1 16384B: Vb[4][64][32] (attn)  /  red1/red2 [64][4] f32 (epilogue)
    __shared__ char smem[53248];
    u16* Sb = (u16*)smem + (size_t)wave * (64 * 72);
    u16* thbf = (u16*)smem;
    u16* Vb = (u16*)(smem + 36864) + (size_t)wave * (64 * 32);
    float* red1 = (float*)(smem + 36864);
    float* red2 = (float*)(smem + 36864 + 1024);
    const size_t base = (size_t)b * (64 * 256);
    float rw[8];
    {
        f32x4 r0 = *(const f32x4*)(rotw + quad * 8);
        f32x4 r1 = *(const f32x4*)(rotw + quad * 8 + 4);
#pragma unroll
        for (int j = 0; j < 4; ++j) { rw[j] = r0[j]; rw[j + 4] = r1[j]; }
    }
    f32x4 acc[4][4];
#pragma unroll
    for (int mi = 0; mi < 4; ++mi)
#pragma unroll
        for (int ni = 0; ni < 4; ++ni) acc[mi][ni] = f32x4{0.f, 0.f, 0.f, 0.f};

    for (int t = 0; t < 2; ++t) {
        int h = wave * 2 + t;
        const u16* qh = qws + base + h * 32;
        const u16* kh = kws + base + h * 32;
        const u16* vh = vws + base + h * 32;
#pragma unroll
        for (int i = 0; i < 4; ++i) {
            int row = i * 16 + (lane >> 2); int c8 = (lane & 3) * 8;
            *(u16x8*)&Vb[row * 32 + c8] = *(const u16x8*)(vh + (size_t)row * 256 + c8);
        }
        // q fragments (rot-weighted cos/sin)
        bf16x8 af[4][2];
#pragma unroll
        for (int mi = 0; mi < 4; ++mi) {
            u16x8 q8 = *(const u16x8*)(qh + (size_t)(mi * 16 + l15) * 256 + quad * 8);
            float cq[8], sq[8];
#pragma unroll
            for (int j = 0; j < 8; ++j) {
                float v = b2f(q8[j]) * INV2PI;
                cq[j] = __builtin_amdgcn_cosf(v);
                sq[j] = __builtin_amdgcn_sinf(v);
            }
            u16x8 cv, sv;
#pragma unroll
            for (int j2 = 0; j2 < 4; ++j2) {
                ((unsigned*)&cv)[j2] = pkb(cq[2 * j2] * rw[2 * j2], cq[2 * j2 + 1] * rw[2 * j2 + 1]);
                ((unsigned*)&sv)[j2] = pkb(sq[2 * j2] * rw[2 * j2], sq[2 * j2 + 1] * rw[2 * j2 + 1]);
            }
            af[mi][0] = __builtin_bit_cast(bf16x8, cv);
            af[mi][1] = __builtin_bit_cast(bf16x8, sv);
        }
        // logits + sigmoid in two ni-halves (register pressure)
#pragma unroll
        for (int nh = 0; nh < 2; ++nh) {
            bf16x8 bfr[2][2];
#pragma unroll
            for (int nj = 0; nj < 2; ++nj) {
                int ni = nh * 2 + nj;
                u16x8 k8 = *(const u16x8*)(kh + (size_t)(ni * 16 + l15) * 256 + quad * 8);
                float ck[8], sk[8];
#pragma unroll
                for (int j = 0; j < 8; ++j) {
                    float v = b2f(k8[j]) * INV2PI;
                    ck[j] = __builtin_amdgcn_cosf(v);
                    sk[j] = __builtin_amdgcn_sinf(v);
                }
                u16x8 cv, sv;
#pragma unroll
                for (int j2 = 0; j2 < 4; ++j2) {
                    ((unsigned*)&cv)[j2] = pkb(ck[2 * j2], ck[2 * j2 + 1]);
                    ((unsigned*)&sv)[j2] = pkb(sk[2 * j2], sk[2 * j2 + 1]);
                }
                bfr[nj][0] = __builtin_bit_cast(bf16x8, cv);
                bfr[nj][1] = __builtin_bit_cast(bf16x8, sv);
            }
            f32x4 lacc[4][2];
#pragma unroll
            for (int mi = 0; mi < 4; ++mi)
#pragma unroll
                for (int nj = 0; nj < 2; ++nj) lacc[mi][nj] = f32x4{0.f, 0.f, 0.f, 0.f};
#pragma unroll
            for (int kc = 0; kc < 2; ++kc)
#pragma unroll
                for (int mi = 0; mi < 4; ++mi)
#pragma unroll
                    for (int nj = 0; nj < 2; ++nj)
                        lacc[mi][nj] = __builtin_amdgcn_mfma_f32_16x16x32_bf16(af[mi][kc], bfr[nj][kc], lacc[mi][nj], 0, 0, 0);
#pragma unroll
            for (int mi = 0; mi < 4; ++mi)
#pragma unroll
                for (int nj = 0; nj < 2; ++nj)
#pragma unroll
                    for (int r = 0; r < 4; ++r) {
                        float x = lacc[mi][nj][r];
                        float sg = __builtin_amdgcn_rcpf(1.f + __builtin_amdgcn_exp2f(-LOG2E * x));
                        Sb[(mi * 16 + quad * 4 + r) * 72 + (nh * 2 + nj) * 16 + l15] = f2b(sg);
                    }
        }
        // PV: accumulate straight into the GEMM accumulator slice
#pragma unroll
        for (int kc = 0; kc < 2; ++kc) {
            bf16x8 pb[2];
#pragma unroll
            for (int n2 = 0; n2 < 2; ++n2)
#pragma unroll
                for (int j = 0; j < 8; ++j)
                    pb[n2][j] = (short)Vb[(kc * 32 + quad * 8 + j) * 32 + n2 * 16 + l15];
#pragma unroll
            for (int mi = 0; mi < 4; ++mi) {
                bf16x8 pa = *(const bf16x8*)&Sb[(mi * 16 + l15) * 72 + kc * 32 + quad * 8];
#pragma unroll
                for (int n2 = 0; n2 < 2; ++n2)
                    acc[mi][t * 2 + n2] = __builtin_amdgcn_mfma_f32_16x16x32_bf16(pa, pb[n2], acc[mi][t * 2 + n2], 0, 0, 0);
            }
        }
    }
    __syncthreads();  // attention done in all waves; Sb/Vb regions now dead
    // stage theta[b] 64x256 f32 -> bf16 swizzled into region0
    const float* thb = theta + base;
#pragma unroll
    for (int p = 0; p < 8; ++p) {
        int id = p * 256 + tid;
        int r = id >> 5, c = id & 31;
        const float* g = thb + (size_t)r * 256 + c * 8;
        f32x4 a = *(const f32x4*)g, bb = *(const f32x4*)(g + 4);
        u16x8 v;
        ((unsigned*)&v)[0] = pkb(a[0], a[1]); ((unsigned*)&v)[1] = pkb(a[2], a[3]);
        ((unsigned*)&v)[2] = pkb(bb[0], bb[1]); ((unsigned*)&v)[3] = pkb(bb[2], bb[3]);
        *(u16x8*)&thbf[r * 256 + ((c ^ (r & 7)) * 8)] = v;
    }
    __syncthreads();
    // GEMM: res += theta @ WlB^T (M=64 rows, wave owns N-slice wn0)
#pragma unroll
    for (int kk = 0; kk < 8; ++kk) {
        bf16x8 af2[4], bfr2[4];
#pragma unroll
        for (int mi = 0; mi < 4; ++mi) {
            int row = mi * 16 + l15;
            int pos = (kk * 4 + quad) ^ (l15 & 7);
            af2[mi] = *(const bf16x8*)&thbf[row * 256 + pos * 8];
        }
#pragma unroll
        for (int ni = 0; ni < 4; ++ni)
            bfr2[ni] = *(const bf16x8*)(WlB + (size_t)(wn0 + ni * 16 + l15) * 256 + kk * 32 + quad * 8);
#pragma unroll
        for (int mi = 0; mi < 4; ++mi)
#pragma unroll
            for (int ni = 0; ni < 4; ++ni)
                acc[mi][ni] = __builtin_amdgcn_mfma_f32_16x16x32_bf16(af2[mi], bfr2[ni], acc[mi][ni], 0, 0, 0);
    }
    // LayerNorm epilogue: row stats across 4 waves (red arrays overlay dead Vb region)
    float gam[4], bet[4];
#pragma unroll
    for (int ni = 0; ni < 4; ++ni) {
        gam[ni] = gamma[wn0 + ni * 16 + l15];
        bet[ni] = beta[wn0 + ni * 16 + l15];
    }
#pragma unroll
    for (int mi = 0; mi < 4; ++mi)
#pragma unroll
        for (int r = 0; r < 4; ++r) {
            float s1 = 0.f, s2 = 0.f;
#pragma unroll
            for (int ni = 0; ni < 4; ++ni) { float x = acc[mi][ni][r]; s1 += x; s2 += x * x; }
#pragma unroll
            for (int off = 1; off < 16; off <<= 1) {
                s1 += __shfl_xor(s1, off);
                s2 += __shfl_xor(s2, off);
            }
            if (l15 == 0) {
                int lr = mi * 16 + quad * 4 + r;
                red1[lr * 4 + wave] = s1; red2[lr * 4 + wave] = s2;
            }
        }
    __syncthreads();
#pragma unroll
    for (int mi = 0; mi < 4; ++mi)
#pragma unroll
        for (int r = 0; r < 4; ++r) {
            int lr = mi * 16 + quad * 4 + r;
            float s1 = red1[lr * 4] + red1[lr * 4 + 1] + red1[lr * 4 + 2] + red1[lr * 4 + 3];
            float s2 = red2[lr * 4] + red2[lr * 4 + 1] + red2[lr * 4 + 2] + red2[lr * 4 + 3];
            float mu = s1 * (1.f / 256.f);
            float var = s2 * (1.f / 256.f) - mu * mu;
            float inv = rsqrtf(var + 1e-5f);
#pragma unroll
            for (int ni = 0; ni < 4; ++ni) {
                float y = (acc[mi][ni][r] - mu) * inv * gam[ni] + bet[ni];
                out[base + (size_t)lr * 256 + wn0 + ni * 16 + l15] = y;
            }
        }
}

extern "C" void kernel_launch(void* const* d_in, const int* in_sizes, int n_in,
                              void* d_out, int out_size, void* d_ws, size_t ws_size,
                              hipStream_t stream)
{
    const float* theta = (const float*)d_in[0];
    const float* Q  = (const float*)d_in[1];
    const float* K  = (const float*)d_in[2];
    const float* V  = (const float*)d_in[3];
    const float* Wl = (const float*)d_in[4];
    const float* rotw = (const float*)d_in[5];
    const float* gam = (const float*)d_in[6];
    const float* bet = (const float*)d_in[7];
    int B = in_sizes[0] / (64 * 256);  // 1024
    u16* ws = (u16*)d_ws;
    size_t per = (size_t)B * 16384;
    u16* wsq = ws;
    u16* wsk = ws + per;
    u16* wsv = ws + 2 * per;
    u16* wT  = ws + 3 * per;             // 192 transposed bf16 256x256 mats (24.6MB)
    u16* wlb = wT + (size_t)192 * 65536; // bf16 W_lin (128KB)
    float* outf = (float*)d_out;

    wtrans_kernel<<<dim3(4, 4, 193), 256, 0, stream>>>(Q, K, V, Wl, wT, wlb);
    qkv_gemm_kernel<<<dim3(B / 128, 2, 64), 256, 0, stream>>>(theta, wT, ws, B);
    attn_lin_kernel<<<dim3(B), 256, 0, stream>>>(wsq, wsk, wsv, theta, wlb, gam, bet, rotw, outf);
}

// Round 7
// 256.948 us; speedup vs baseline: 1.3288x; 1.3288x over previous
//
#include <hip/hip_runtime.h>

// Problem: B=1024, F=64, D_IN=D_OUT=256, H=8, dh=32. f32 in/out, bf16 MFMA compute.
typedef __attribute__((ext_vector_type(8))) short bf16x8;
typedef __attribute__((ext_vector_type(8))) unsigned short u16x8;
typedef __attribute__((ext_vector_type(4))) unsigned short u16x4;
typedef __attribute__((ext_vector_type(4))) float f32x4;
typedef unsigned short u16;

__device__ __forceinline__ float b2f(u16 u) {
    return __builtin_bit_cast(float, (unsigned)u << 16);
}
__device__ __forceinline__ u16 f2b(float f) {  // RNE f32->bf16
    unsigned i = __builtin_bit_cast(unsigned, f);
    return (u16)((i + 0x7FFFu + ((i >> 16) & 1u)) >> 16);
}
__device__ __forceinline__ unsigned pkb(float a, float b) {
    return (unsigned)f2b(a) | ((unsigned)f2b(b) << 16);
}
__device__ __forceinline__ void async_cp16(const u16* g, u16* l) {
    __builtin_amdgcn_global_load_lds((const __attribute__((address_space(1))) void*)g,
                                     (__attribute__((address_space(3))) void*)l, 16, 0, 0);
}

// ---- kernel 0: f32 weights [d][w] -> bf16 WT [w][d]; z==192 converts W_lin (no transpose)
__global__ __launch_bounds__(256) void wtrans_kernel(
    const float* __restrict__ Q, const float* __restrict__ K, const float* __restrict__ V,
    const float* __restrict__ Wl, u16* __restrict__ WT, u16* __restrict__ WlB)
{
    int z = blockIdx.z;
    int tid = threadIdx.x;
    if (z == 192) {  // W_lin [w][d] already B-operand layout; dtype-convert only
        int w0 = blockIdx.x * 64, d0 = blockIdx.y * 64;
#pragma unroll
        for (int i = 0; i < 2; ++i) {
            int idx = tid * 2 + i; int r = idx >> 3; int c8 = (idx & 7) * 8;
            const float* p = Wl + (size_t)(w0 + r) * 256 + d0 + c8;
            f32x4 a = *(const f32x4*)p, b = *(const f32x4*)(p + 4);
            u16x8 v;
            ((unsigned*)&v)[0] = pkb(a[0], a[1]); ((unsigned*)&v)[1] = pkb(a[2], a[3]);
            ((unsigned*)&v)[2] = pkb(b[0], b[1]); ((unsigned*)&v)[3] = pkb(b[2], b[3]);
            *(u16x8*)(WlB + (size_t)(w0 + r) * 256 + d0 + c8) = v;
        }
        return;
    }
    if (z > 192) return;
    int m = z >> 6, f = z & 63;
    const float* src = (m == 0 ? Q : (m == 1 ? K : V)) + (size_t)f * 65536;
    u16* dst = WT + (size_t)z * 65536;
    int w0 = blockIdx.x * 64, d0 = blockIdx.y * 64;
    __shared__ u16 tile[64][68];
#pragma unroll
    for (int i = 0; i < 2; ++i) {
        int idx = tid * 2 + i; int r = idx >> 3; int c8 = (idx & 7) * 8;
        const float* p = src + (size_t)(d0 + r) * 256 + w0 + c8;
        f32x4 a = *(const f32x4*)p, b = *(const f32x4*)(p + 4);
        u16x4 lo, hi;
        ((unsigned*)&lo)[0] = pkb(a[0], a[1]); ((unsigned*)&lo)[1] = pkb(a[2], a[3]);
        ((unsigned*)&hi)[0] = pkb(b[0], b[1]); ((unsigned*)&hi)[1] = pkb(b[2], b[3]);
        *(u16x4*)&tile[r][c8] = lo;
        *(u16x4*)&tile[r][c8 + 4] = hi;
    }
    __syncthreads();
#pragma unroll
    for (int i = 0; i < 2; ++i) {
        int idx = tid * 2 + i; int rw = idx >> 3; int c8 = (idx & 7) * 8;
        u16x8 v;
#pragma unroll
        for (int j = 0; j < 8; ++j) v[j] = tile[c8 + j][rw];
        *(u16x8*)(dst + (size_t)(w0 + rw) * 256 + d0 + c8) = v;
    }
}

// ---- kernel 1: q,k,v per f, m fused. A staged once (swizzled LDS -> regs);
// B via global_load_lds double-buffer, BK=64 (32 MFMA per barrier).
__global__ __launch_bounds__(256, 2) void qkv_gemm_kernel(
    const float* __restrict__ theta, const u16* __restrict__ WT, u16* __restrict__ ws, int B)
{
    int f = blockIdx.z;
    int bm0 = blockIdx.x * 128, bn0 = blockIdx.y * 128;
    __shared__ u16 smem[128 * 256];  // 64KB: phase1 A-tile; phase2 B dbuf 2x16KB
    int tid = threadIdx.x, wave = tid >> 6, lane = tid & 63;
    int l15 = lane & 15, quad = lane >> 4;
    int wm0 = (wave >> 1) * 64, wn0 = (wave & 1) * 64;

    const float* Af = theta + (size_t)f * 256;
#pragma unroll
    for (int p = 0; p < 16; ++p) {
        int id = p * 256 + tid;
        int r = id >> 5, c = id & 31;
        const float* g = Af + (size_t)(bm0 + r) * 16384 + c * 8;
        f32x4 a = *(const f32x4*)g, b = *(const f32x4*)(g + 4);
        u16x8 v;
        ((unsigned*)&v)[0] = pkb(a[0], a[1]); ((unsigned*)&v)[1] = pkb(a[2], a[3]);
        ((unsigned*)&v)[2] = pkb(b[0], b[1]); ((unsigned*)&v)[3] = pkb(b[2], b[3]);
        *(u16x8*)&smem[r * 256 + ((c ^ (r & 7)) * 8)] = v;
    }
    __syncthreads();
    bf16x8 af[4][8];
#pragma unroll
    for (int mi = 0; mi < 4; ++mi)
#pragma unroll
        for (int kk = 0; kk < 8; ++kk) {
            int row = wm0 + mi * 16 + l15;
            int pos = (kk * 4 + quad) ^ (l15 & 7);
            af[mi][kk] = *(const bf16x8*)&smem[row * 256 + pos * 8];
        }
    __syncthreads();  // A reads done before B dbuf overwrites smem

    // 12 iterations: it = m*4 + kp (kp = K-pair index, BK=64)
    auto issueB = [&](int it) {
        int m = it >> 2, kp = it & 3, buf = it & 1;
        const u16* Bt = WT + (size_t)(m * 64 + f) * 65536;
#pragma unroll
        for (int s = 0; s < 2; ++s)
#pragma unroll
            for (int i = 0; i < 2; ++i) {
                int r0 = wave * 32 + i * 16;
                const u16* g = Bt + (size_t)(bn0 + r0 + (lane >> 2)) * 256 + (kp * 2 + s) * 32 + (lane & 3) * 8;
                async_cp16(g, &smem[buf * 8192 + s * 4096 + r0 * 32]);
            }
    };
    issueB(0);
    f32x4 acc[4][4];
#pragma unroll
    for (int it = 0; it < 12; ++it) {
        int kp = it & 3, buf = it & 1;
        if (kp == 0) {
#pragma unroll
            for (int mi = 0; mi < 4; ++mi)
#pragma unroll
                for (int ni = 0; ni < 4; ++ni) acc[mi][ni] = f32x4{0.f, 0.f, 0.f, 0.f};
        }
        __syncthreads();             // current buffer landed
        if (it < 11) issueB(it + 1);
#pragma unroll
        for (int s = 0; s < 2; ++s) {
            bf16x8 bfr[4];
#pragma unroll
            for (int ni = 0; ni < 4; ++ni)
                bfr[ni] = *(const bf16x8*)&smem[buf * 8192 + s * 4096 + (wn0 + ni * 16 + l15) * 32 + quad * 8];
#pragma unroll
            for (int mi = 0; mi < 4; ++mi)
#pragma unroll
                for (int ni = 0; ni < 4; ++ni)
                    acc[mi][ni] = __builtin_amdgcn_mfma_f32_16x16x32_bf16(af[mi][kp * 2 + s], bfr[ni], acc[mi][ni], 0, 0, 0);
        }
        if (kp == 3) {
            int m = it >> 2;
            u16* C = ws + (size_t)m * B * 16384 + (size_t)f * 256;
#pragma unroll
            for (int mi = 0; mi < 4; ++mi)
#pragma unroll
                for (int ni = 0; ni < 4; ++ni)
#pragma unroll
                    for (int r = 0; r < 4; ++r)
                        C[(size_t)(bm0 + wm0 + mi * 16 + quad * 4 + r) * 16384 + bn0 + wn0 + ni * 16 + l15] =
                            f2b(acc[mi][ni][r]);
        }
    }
}

// ---- kernel 2: FUSED attention + linear + LayerNorm. One block per b, 4 waves.
// Wave w handles heads 2w,2w+1 -> attention output lands exactly in the GEMM
// accumulator slice (cols w*64..w*64+63): acc[mi][t*2+n2]. Then res += theta@WlB^T, LN.
__global__ __launch_bounds__(256, 2) void attn_lin_kernel(
    const u16* __restrict__ qws, const u16* __restrict__ kws, const u16* __restrict__ vws,
    const float* __restrict__ theta, const u16* __restrict__ WlB,
    const float* __restrict__ gamma, const float* __restrict__ beta,
    const float* __restrict__ rotw, float* __restrict__ out)
{
    constexpr float INV2PI = 0.15915494309189535f;
    constexpr float LOG2E = 1.4426950408889634f;
    int b = blockIdx.x;
    int tid = threadIdx.x, wave = tid >> 6, lane = tid & 63;
    int l15 = lane & 15, quad = lane >> 4;
    int wn0 = wave * 64;
    // LDS 52KB total -> region0 36864B: Sb (attn) / thbf (gemm); region1 16KB: Vb / red.
    __shared__ char smem[53248];
    u16* Sb = (u16*)smem + (size_t)wave * (64 * 72);
    u16* thbf = (u16*)smem;
    u16* Vb = (u16*)(smem + 36864) + (size_t)wave * (64 * 32);
    float* red1 = (float*)(smem + 36864);
    float* red2 = (float*)(smem + 36864 + 1024);
    const size_t base = (size_t)b * (64 * 256);
    float rw[8];
    {
        f32x4 r0 = *(const f32x4*)(rotw + quad * 8);
        f32x4 r1 = *(const f32x4*)(rotw + quad * 8 + 4);
#pragma unroll
        for (int j = 0; j < 4; ++j) { rw[j] = r0[j]; rw[j + 4] = r1[j]; }
    }
    f32x4 acc[4][4];
#pragma unroll
    for (int mi = 0; mi < 4; ++mi)
#pragma unroll
        for (int ni = 0; ni < 4; ++ni) acc[mi][ni] = f32x4{0.f, 0.f, 0.f, 0.f};

#pragma unroll  // CRITICAL: t must be compile-time so acc[mi][t*2+n2] stays in registers
    for (int t = 0; t < 2; ++t) {
        int h = wave * 2 + t;
        const u16* qh = qws + base + h * 32;
        const u16* kh = kws + base + h * 32;
        const u16* vh = vws + base + h * 32;
#pragma unroll
        for (int i = 0; i < 4; ++i) {
            int row = i * 16 + (lane >> 2); int c8 = (lane & 3) * 8;
            *(u16x8*)&Vb[row * 32 + c8] = *(const u16x8*)(vh + (size_t)row * 256 + c8);
        }
        // q fragments (rot-weighted cos/sin)
        bf16x8 af[4][2];
#pragma unroll
        for (int mi = 0; mi < 4; ++mi) {
            u16x8 q8 = *(const u16x8*)(qh + (size_t)(mi * 16 + l15) * 256 + quad * 8);
            float cq[8], sq[8];
#pragma unroll
            for (int j = 0; j < 8; ++j) {
                float v = b2f(q8[j]) * INV2PI;
                cq[j] = __builtin_amdgcn_cosf(v);
                sq[j] = __builtin_amdgcn_sinf(v);
            }
            u16x8 cv, sv;
#pragma unroll
            for (int j2 = 0; j2 < 4; ++j2) {
                ((unsigned*)&cv)[j2] = pkb(cq[2 * j2] * rw[2 * j2], cq[2 * j2 + 1] * rw[2 * j2 + 1]);
                ((unsigned*)&sv)[j2] = pkb(sq[2 * j2] * rw[2 * j2], sq[2 * j2 + 1] * rw[2 * j2 + 1]);
            }
            af[mi][0] = __builtin_bit_cast(bf16x8, cv);
            af[mi][1] = __builtin_bit_cast(bf16x8, sv);
        }
        // logits + sigmoid in two ni-halves (register pressure)
#pragma unroll
        for (int nh = 0; nh < 2; ++nh) {
            bf16x8 bfr[2][2];
#pragma unroll
            for (int nj = 0; nj < 2; ++nj) {
                int ni = nh * 2 + nj;
                u16x8 k8 = *(const u16x8*)(kh + (size_t)(ni * 16 + l15) * 256 + quad * 8);
                float ck[8], sk[8];
#pragma unroll
                for (int j = 0; j < 8; ++j) {
                    float v = b2f(k8[j]) * INV2PI;
                    ck[j] = __builtin_amdgcn_cosf(v);
                    sk[j] = __builtin_amdgcn_sinf(v);
                }
                u16x8 cv, sv;
#pragma unroll
                for (int j2 = 0; j2 < 4; ++j2) {
                    ((unsigned*)&cv)[j2] = pkb(ck[2 * j2], ck[2 * j2 + 1]);
                    ((unsigned*)&sv)[j2] = pkb(sk[2 * j2], sk[2 * j2 + 1]);
                }
                bfr[nj][0] = __builtin_bit_cast(bf16x8, cv);
                bfr[nj][1] = __builtin_bit_cast(bf16x8, sv);
            }
            f32x4 lacc[4][2];
#pragma unroll
            for (int mi = 0; mi < 4; ++mi)
#pragma unroll
                for (int nj = 0; nj < 2; ++nj) lacc[mi][nj] = f32x4{0.f, 0.f, 0.f, 0.f};
#pragma unroll
            for (int kc = 0; kc < 2; ++kc)
#pragma unroll
                for (int mi = 0; mi < 4; ++mi)
#pragma unroll
                    for (int nj = 0; nj < 2; ++nj)
                        lacc[mi][nj] = __builtin_amdgcn_mfma_f32_16x16x32_bf16(af[mi][kc], bfr[nj][kc], lacc[mi][nj], 0, 0, 0);
#pragma unroll
            for (int mi = 0; mi < 4; ++mi)
#pragma unroll
                for (int nj = 0; nj < 2; ++nj)
#pragma unroll
                    for (int r = 0; r < 4; ++r) {
                        float x = lacc[mi][nj][r];
                        float sg = __builtin_amdgcn_rcpf(1.f + __builtin_amdgcn_exp2f(-LOG2E * x));
                        Sb[(mi * 16 + quad * 4 + r) * 72 + (nh * 2 + nj) * 16 + l15] = f2b(sg);
                    }
        }
        // PV: accumulate straight into the GEMM accumulator slice
#pragma unroll
        for (int kc = 0; kc < 2; ++kc) {
            bf16x8 pb[2];
#pragma unroll
            for (int n2 = 0; n2 < 2; ++n2)
#pragma unroll
                for (int j = 0; j < 8; ++j)
                    pb[n2][j] = (short)Vb[(kc * 32 + quad * 8 + j) * 32 + n2 * 16 + l15];
#pragma unroll
            for (int mi = 0; mi < 4; ++mi) {
                bf16x8 pa = *(const bf16x8*)&Sb[(mi * 16 + l15) * 72 + kc * 32 + quad * 8];
#pragma unroll
                for (int n2 = 0; n2 < 2; ++n2)
                    acc[mi][t * 2 + n2] = __builtin_amdgcn_mfma_f32_16x16x32_bf16(pa, pb[n2], acc[mi][t * 2 + n2], 0, 0, 0);
            }
        }
    }
    __syncthreads();  // attention done in all waves; Sb/Vb regions now dead
    // stage theta[b] 64x256 f32 -> bf16 swizzled into region0
    const float* thb = theta + base;
#pragma unroll
    for (int p = 0; p < 8; ++p) {
        int id = p * 256 + tid;
        int r = id >> 5, c = id & 31;
        const float* g = thb + (size_t)r * 256 + c * 8;
        f32x4 a = *(const f32x4*)g, bb = *(const f32x4*)(g + 4);
        u16x8 v;
        ((unsigned*)&v)[0] = pkb(a[0], a[1]); ((unsigned*)&v)[1] = pkb(a[2], a[3]);
        ((unsigned*)&v)[2] = pkb(bb[0], bb[1]); ((unsigned*)&v)[3] = pkb(bb[2], bb[3]);
        *(u16x8*)&thbf[r * 256 + ((c ^ (r & 7)) * 8)] = v;
    }
    __syncthreads();
    // GEMM: res += theta @ WlB^T (M=64 rows, wave owns N-slice wn0)
#pragma unroll
    for (int kk = 0; kk < 8; ++kk) {
        bf16x8 af2[4], bfr2[4];
#pragma unroll
        for (int mi = 0; mi < 4; ++mi) {
            int row = mi * 16 + l15;
            int pos = (kk * 4 + quad) ^ (l15 & 7);
            af2[mi] = *(const bf16x8*)&thbf[row * 256 + pos * 8];
        }
#pragma unroll
        for (int ni = 0; ni < 4; ++ni)
            bfr2[ni] = *(const bf16x8*)(WlB + (size_t)(wn0 + ni * 16 + l15) * 256 + kk * 32 + quad * 8);
#pragma unroll
        for (int mi = 0; mi < 4; ++mi)
#pragma unroll
            for (int ni = 0; ni < 4; ++ni)
                acc[mi][ni] = __builtin_amdgcn_mfma_f32_16x16x32_bf16(af2[mi], bfr2[ni], acc[mi][ni], 0, 0, 0);
    }
    // LayerNorm epilogue: row stats across 4 waves (red arrays overlay dead Vb region)
    float gam[4], bet[4];
#pragma unroll
    for (int ni = 0; ni < 4; ++ni) {
        gam[ni] = gamma[wn0 + ni * 16 + l15];
        bet[ni] = beta[wn0 + ni * 16 + l15];
    }
#pragma unroll
    for (int mi = 0; mi < 4; ++mi)
#pragma unroll
        for (int r = 0; r < 4; ++r) {
            float s1 = 0.f, s2 = 0.f;
#pragma unroll
            for (int ni = 0; ni < 4; ++ni) { float x = acc[mi][ni][r]; s1 += x; s2 += x * x; }
#pragma unroll
            for (int off = 1; off < 16; off <<= 1) {
                s1 += __shfl_xor(s1, off);
                s2 += __shfl_xor(s2, off);
            }
            if (l15 == 0) {
                int lr = mi * 16 + quad * 4 + r;
                red1[lr * 4 + wave] = s1; red2[lr * 4 + wave] = s2;
            }
        }
    __syncthreads();
#pragma unroll
    for (int mi = 0; mi < 4; ++mi)
#pragma unroll
        for (int r = 0; r < 4; ++r) {
            int lr = mi * 16 + quad * 4 + r;
            float s1 = red1[lr * 4] + red1[lr * 4 + 1] + red1[lr * 4 + 2] + red1[lr * 4 + 3];
            float s2 = red2[lr * 4] + red2[lr * 4 + 1] + red2[lr * 4 + 2] + red2[lr * 4 + 3];
            float mu = s1 * (1.f / 256.f);
            float var = s2 * (1.f / 256.f) - mu * mu;
            float inv = rsqrtf(var + 1e-5f);
#pragma unroll
            for (int ni = 0; ni < 4; ++ni) {
                float y = (acc[mi][ni][r] - mu) * inv * gam[ni] + bet[ni];
                out[base + (size_t)lr * 256 + wn0 + ni * 16 + l15] = y;
            }
        }
}

extern "C" void kernel_launch(void* const* d_in, const int* in_sizes, int n_in,
                              void* d_out, int out_size, void* d_ws, size_t ws_size,
                              hipStream_t stream)
{
    const float* theta = (const float*)d_in[0];
    const float* Q  = (const float*)d_in[1];
    const float* K  = (const float*)d_in[2];
    const float* V  = (const float*)d_in[3];
    const float* Wl = (const float*)d_in[4];
    const float* rotw = (const float*)d_in[5];
    const float* gam = (const float*)d_in[6];
    const float* bet = (const float*)d_in[7];
    int B = in_sizes[0] / (64 * 256);  // 1024
    u16* ws = (u16*)d_ws;
    size_t per = (size_t)B * 16384;
    u16* wsq = ws;
    u16* wsk = ws + per;
    u16* wsv = ws + 2 * per;
    u16* wT  = ws + 3 * per;             // 192 transposed bf16 256x256 mats (24.6MB)
    u16* wlb = wT + (size_t)192 * 65536; // bf16 W_lin (128KB)
    float* outf = (float*)d_out;

    wtrans_kernel<<<dim3(4, 4, 193), 256, 0, stream>>>(Q, K, V, Wl, wT, wlb);
    qkv_gemm_kernel<<<dim3(B / 128, 2, 64), 256, 0, stream>>>(theta, wT, ws, B);
    attn_lin_kernel<<<dim3(B), 256, 0, stream>>>(wsq, wsk, wsv, theta, wlb, gam, bet, rotw, outf);
}